// Round 15
// baseline (94.742 us; speedup 1.0000x reference)
//
#include <hip/hip_runtime.h>
#include <hip/hip_bf16.h>
#include <math.h>

// Problem constants
#define NB   8
#define TCTX 4096
#define ED   1024
#define KD   64

typedef __attribute__((ext_vector_type(8))) short bf16x8;
typedef __attribute__((ext_vector_type(4))) float f32x4;

#define LOG2E  1.44269504088896340736f
#define SCALE2 (0.125f * LOG2E)          // folded into Q at projection time
#define MASK2  (-1e10f * LOG2E)          // -1e10 in log2 domain

// LGKM ops complete OUT OF ORDER: ds_read after ds_write needs lgkmcnt(0)
// (R8/R9 lesson). Used in proj's H round-trip only (attn has no LDS bounce).
__device__ __forceinline__ void lds_fence() {
    asm volatile("s_waitcnt lgkmcnt(0)" ::: "memory");
    __builtin_amdgcn_sched_barrier(0);
}

__device__ __forceinline__ unsigned short f2bf(float f) {
    union { float f; unsigned u; } c; c.f = f;
    return (unsigned short)((c.u + 0x7FFFu + ((c.u >> 16) & 1u)) >> 16);
}
__device__ __forceinline__ int swz(int row, int byteoff) {
    return row * 128 + (byteoff ^ ((row & 7) << 4));
}
__device__ __forceinline__ f32x4 fzero4() {
    f32x4 z; z[0] = 0.f; z[1] = 0.f; z[2] = 0.f; z[3] = 0.f; return z;
}
__device__ __forceinline__ void gl_lds16(const void* g, void* l) {
    __builtin_amdgcn_global_load_lds(
        (const __attribute__((address_space(1))) unsigned int*)g,
        (__attribute__((address_space(3))) unsigned int*)l, 16, 0, 0);
}
__device__ __forceinline__ unsigned cvtpk_bf16(float lo, float hi) {
    unsigned r;
    asm("v_cvt_pk_bf16_f32 %0, %1, %2" : "=v"(r) : "v"(lo), "v"(hi));
    return r;
}

// ---------------------------------------------------------------------------
// Prep kernel: one-time weight repack (fp32 -> bf16).  (unchanged, passing)
// ---------------------------------------------------------------------------
__global__ __launch_bounds__(256) void prep_kernel(
    const float* __restrict__ kw1, const float* __restrict__ qw1,
    const float* __restrict__ vw,  const float* __restrict__ kw2,
    const float* __restrict__ qw2,
    unsigned short* __restrict__ W1p, unsigned short* __restrict__ W2p)
{
    int idx = blockIdx.x * 256 + threadIdx.x;   // 16B-block index
    if (idx < 24576) {
        int ks = idx / 1536, rem = idx % 1536;
        int r = rem >> 3, bb = rem & 7;
        int c = bb ^ (r & 7);
        const float* src = (r < 64)  ? (kw1 + r * ED)
                         : (r < 128) ? (qw1 + (r - 64) * ED)
                                     : (vw  + (r - 128) * ED);
        src += ks * 64 + c * 8;
        unsigned short* dst = W1p + (size_t)idx * 8;
        #pragma unroll
        for (int e = 0; e < 8; ++e) dst[e] = f2bf(src[e]);
    } else if (idx < 25600) {
        int j = idx - 24576;
        int lane = j & 63, kh = (j >> 6) & 1, n = (j >> 7) & 3, kq = j >> 9;
        int row = n * 16 + (lane & 15);
        int ko  = kh * 32 + (lane >> 4) * 8;
        const float* src = (kq ? qw2 : kw2) + row * 64 + ko;
        unsigned short* dst = W2p + (size_t)j * 8;
        #pragma unroll
        for (int e = 0; e < 8; ++e) dst[e] = f2bf(src[e]);
    }
}

// ---------------------------------------------------------------------------
// Projection kernel (unchanged, passing).
// ---------------------------------------------------------------------------
__global__ __launch_bounds__(256, 2) void proj_kernel(
    const float* __restrict__ emb,
    const unsigned short* __restrict__ W1p, const unsigned short* __restrict__ W2p,
    const float* __restrict__ kb1, const float* __restrict__ kb2,
    const float* __restrict__ qb1, const float* __restrict__ qb2,
    const float* __restrict__ vb,
    unsigned short* __restrict__ Qo, unsigned short* __restrict__ Ko,
    unsigned short* __restrict__ Vt)
{
    __shared__ __align__(16) char lds[80 * 1024];

    const int tid  = threadIdx.x;
    const int lane = tid & 63;
    const int w    = tid >> 6;
    const int lr   = lane & 15;
    const int lg   = lane >> 4;
    const long r0  = (long)blockIdx.x * 64;
    const int  b   = blockIdx.x >> 6;
    const int  tb  = (blockIdx.x & 63) * 64;

    const float* embB = emb + r0 * ED;

    f32x4 acc[12];
    #pragma unroll
    for (int j = 0; j < 12; ++j) acc[j] = fzero4();

    auto stageA = [&](int buf, int ks) {
        char* Abuf = lds + buf * 16 * 1024;
        const float* eb = embB + ks * 64;
        #pragma unroll
        for (int j = 0; j < 4; ++j) {
            int chunk = j * 4 + w;
            int r = chunk * 4 + (lane >> 4);
            int c = (lane & 15) ^ (r & 7);
            gl_lds16(eb + (long)r * ED + c * 4, Abuf + chunk * 1024);
        }
    };
    auto stageB = [&](int buf, int ks) {
        char* Bbuf = lds + 32 * 1024 + buf * 24 * 1024;
        const unsigned short* wb = W1p + (size_t)ks * 12288;
        #pragma unroll
        for (int j = 0; j < 6; ++j) {
            int chunk = j * 4 + w;
            gl_lds16(wb + chunk * 512 + lane * 8, Bbuf + chunk * 1024);
        }
    };

    stageA(0, 0); stageB(0, 0);
    __syncthreads();

    int cur = 0;
    for (int ks = 0; ks < 16; ++ks) {
        if (ks < 15) { stageA(cur ^ 1, ks + 1); stageB(cur ^ 1, ks + 1); }
        char* Ac = lds + cur * 16 * 1024;
        char* Bc = lds + 32 * 1024 + cur * 24 * 1024;
        const int r = w * 16 + lr;
        #pragma unroll
        for (int kh = 0; kh < 2; ++kh) {
            int cb0 = kh * 8 + lg * 2;
            float4 fa = *(const float4*)(Ac + r * 256 + ((cb0 ^ (r & 7)) * 16));
            float4 fb = *(const float4*)(Ac + r * 256 + (((cb0 + 1) ^ (r & 7)) * 16));
            bf16x8 a;
            a[0] = (short)f2bf(fa.x); a[1] = (short)f2bf(fa.y);
            a[2] = (short)f2bf(fa.z); a[3] = (short)f2bf(fa.w);
            a[4] = (short)f2bf(fb.x); a[5] = (short)f2bf(fb.y);
            a[6] = (short)f2bf(fb.z); a[7] = (short)f2bf(fb.w);
            #pragma unroll
            for (int n = 0; n < 12; ++n) {
                bf16x8 bv = *(const bf16x8*)(Bc + swz(n * 16 + lr, kh * 64 + lg * 16));
                acc[n] = __builtin_amdgcn_mfma_f32_16x16x32_bf16(a, bv, acc[n], 0, 0, 0);
            }
        }
        __syncthreads();
        cur ^= 1;
    }

    char* H  = lds + w * 2048;
    char* VT = lds + 16 * 1024;

    #pragma unroll
    for (int kq = 0; kq < 2; ++kq) {
        const float* b1 = kq ? qb1 : kb1;
        const float* b2 = kq ? qb2 : kb2;
        unsigned short* dst = kq ? Qo : Ko;
        const float oscale = kq ? SCALE2 : 1.0f;
        #pragma unroll
        for (int n = 0; n < 4; ++n) {
            int col = n * 16 + lr;
            float bias = b1[col];
            #pragma unroll
            for (int rr = 0; rr < 4; ++rr) {
                int row = lg * 4 + rr;
                *(unsigned short*)(H + swz(row, col * 2)) =
                    f2bf(fmaxf(acc[kq * 4 + n][rr] + bias, 0.f));
            }
        }
        lds_fence();
        bf16x8 a2k0 = *(const bf16x8*)(H + swz(lr, 0 * 64 + lg * 16));
        bf16x8 a2k1 = *(const bf16x8*)(H + swz(lr, 1 * 64 + lg * 16));
        lds_fence();

        f32x4 acc2[4];
        #pragma unroll
        for (int n = 0; n < 4; ++n) acc2[n] = fzero4();
        #pragma unroll
        for (int n = 0; n < 4; ++n) {
            bf16x8 w2f0 = *(const bf16x8*)(W2p + ((kq * 4 + n) * 2 + 0) * 512 + lane * 8);
            bf16x8 w2f1 = *(const bf16x8*)(W2p + ((kq * 4 + n) * 2 + 1) * 512 + lane * 8);
            acc2[n] = __builtin_amdgcn_mfma_f32_16x16x32_bf16(a2k0, w2f0, acc2[n], 0, 0, 0);
            acc2[n] = __builtin_amdgcn_mfma_f32_16x16x32_bf16(a2k1, w2f1, acc2[n], 0, 0, 0);
        }
        #pragma unroll
        for (int n = 0; n < 4; ++n) {
            int col = n * 16 + lr;
            float bias = b2[col];
            #pragma unroll
            for (int rr = 0; rr < 4; ++rr) {
                long rg = r0 + w * 16 + lg * 4 + rr;
                dst[rg * KD + col] = f2bf(fmaxf(acc2[n][rr] + bias, 0.f) * oscale);
            }
        }
    }

    #pragma unroll
    for (int n = 0; n < 4; ++n) {
        int col = n * 16 + lr;
        float bias = vb[col];
        #pragma unroll
        for (int rr = 0; rr < 4; ++rr) {
            int tl = w * 16 + lg * 4 + rr;
            *(unsigned short*)(VT + swz(col, tl * 2)) = f2bf(acc[8 + n][rr] + bias);
        }
    }
    __syncthreads();
    #pragma unroll
    for (int it = 0; it < 2; ++it) {
        int c = it * 256 + tid;
        int h = c >> 3, c4 = c & 7;
        *(int4*)(Vt + ((long)b * KD + h) * TCTX + tb + c4 * 8) =
            *(const int4*)(VT + swz(h, c4 * 16));
    }
}

// ---------------------------------------------------------------------------
// Flash attention v9 = v6 (proven best schedule) + occupancy push.
// Changes vs v6 ONLY: (1) Q loaded direct to registers (no QP LDS region);
// (2) P via cross-lane shfl exchange (v8-verified mapping) instead of LDS
// bounce; (3) LDS 20KB->16KB => 10 blocks/CU = 20 waves/CU (5/SIMD), pinned
// by __launch_bounds__(128,5); (4) b=bid&7 pins each batch's K/Vt to one XCD.
// Staging/drain schedule IDENTICAL to v6:
//   tile i: QK^T(K) ; barrier A (drains V(i) issued last tile, K reads done)
//           issue K(i+1) ; softmax ; shfl-exchange ; PV(V)
//           barrier B (drains K(i+1), V reads done) ; issue V(i+1)
// Exchange map (on-device verified in v8): ap[kh] word jj = W[2kh+(lg>>1)]
// [jj&1] from lane ((2*(lg&1)+(jj>>1))<<4)|lr, W[mi][j]=cvtpk(s2v[mi][2j..]).
// ---------------------------------------------------------------------------
__global__ __launch_bounds__(128, 5) void attn_kernel(
    const unsigned short* __restrict__ Qb,
    const unsigned short* __restrict__ Kb,
    const unsigned short* __restrict__ Vt,
    float* __restrict__ Opart, float2* __restrict__ MSum)
{
    __shared__ __align__(16) char lds[16 * 1024];   // K at 0, V at 8KB

    const int bid  = blockIdx.x;
    const int b    = bid & 7;              // XCD-pinned batch
    const int half = (bid >> 3) & 1;
    const int qr   = bid >> 4;             // 0..127
    const int qi   = (qr + 127) & 127;     // heavy tiles launch first
    const int t0   = qi * 32;
    const int tid = threadIdx.x, lane = tid & 63, w = tid >> 6;
    const int lr  = lane & 15, lg = lane >> 4;
    const int tg  = t0 + w * 16 + lr;      // this lane's q-row

    char* Kl = lds;
    char* Vl = lds + 8 * 1024;

    const unsigned short* Qg  = Qb + ((long)b * TCTX + t0 + w * 16) * KD;
    const unsigned short* Kg0 = Kb + (long)b * TCTX * KD;
    const unsigned short* Vg0 = Vt + (long)b * KD * TCTX;

    const int srow = lane >> 3;
    const int sblk = lane & 7;

    // split-s range
    const int s0q = (qi == 127) ? 0 : (qi >> 1);
    const int len = 64 - s0q;
    const int mid = s0q + ((len + 1) >> 1);
    const int s_lo = half ? mid : s0q;
    const int s_hi = half ? 64  : mid;

    auto stageK = [&](int si) {
        const unsigned short* Kg = Kg0 + si * 64 * KD;
        #pragma unroll
        for (int j = 0; j < 4; ++j) {
            int chunk = w * 4 + j;             // 2 waves split 8 chunks
            int r = chunk * 8 + srow;
            int c = sblk ^ (r & 7);
            gl_lds16(Kg + r * KD + c * 8, Kl + chunk * 1024);
        }
    };
    auto stageV = [&](int si) {
        const unsigned short* Vg = Vg0 + si * 64;
        #pragma unroll
        for (int j = 0; j < 4; ++j) {
            int chunk = w * 4 + j;
            int r = chunk * 8 + srow;
            int c = sblk ^ (r & 7);
            gl_lds16(Vg + (long)r * TCTX + c * 8, Vl + chunk * 1024);
        }
    };

    float m2 = MASK2, sum_p = 0.f;             // per-lane partial sum
    f32x4 O[4];
    #pragma unroll
    for (int n = 0; n < 4; ++n) O[n] = fzero4();

    if (s_lo < s_hi) {                          // block-uniform
        // prologue: Q direct to regs; K/V(s_lo) via DMA
        bf16x8 qf[2];
        #pragma unroll
        for (int kh = 0; kh < 2; ++kh)
            qf[kh] = *(const bf16x8*)(Qg + lr * KD + kh * 32 + lg * 8);
        stageK(s_lo);
        stageV(s_lo);
        __syncthreads();                        // K/V resident (qf via vmcnt)

        for (int si = s_lo; si < s_hi; ++si) {
            // ---- QK^T (swapped): C[s][t], t = lr per lane ----
            f32x4 sc[4];
            #pragma unroll
            for (int mi = 0; mi < 4; ++mi) sc[mi] = fzero4();
            __builtin_amdgcn_s_setprio(1);
            #pragma unroll
            for (int kh = 0; kh < 2; ++kh) {
                #pragma unroll
                for (int mi = 0; mi < 4; ++mi) {
                    bf16x8 kf = *(const bf16x8*)(Kl + swz(mi * 16 + lr, kh * 64 + lg * 16));
                    sc[mi] = __builtin_amdgcn_mfma_f32_16x16x32_bf16(kf, qf[kh], sc[mi], 0, 0, 0);
                }
            }
            __builtin_amdgcn_s_setprio(0);

            __syncthreads();                    // A: K reads done; V(si) drained
            if (si + 1 < s_hi) stageK(si + 1);  // K-DMA under softmax+PV

            // ---- mask (scores in exp2 domain via pre-scaled Q) ----
            const int thr = tg - si * 64;       // mask if s_local <= thr
            float s2v[4][4];
            #pragma unroll
            for (int mi = 0; mi < 4; ++mi)
                #pragma unroll
                for (int rr = 0; rr < 4; ++rr) {
                    int sl = mi * 16 + lg * 4 + rr;
                    s2v[mi][rr] = (sl <= thr) ? MASK2 : sc[mi][rr];
                }

            // ---- defer-max online softmax ----
            float pml = s2v[0][0];
            #pragma unroll
            for (int mi = 0; mi < 4; ++mi)
                #pragma unroll
                for (int rr = 0; rr < 4; ++rr) pml = fmaxf(pml, s2v[mi][rr]);

            if (!__all(pml - m2 <= 8.0f)) {     // rare: full rescale
                float pm = pml;
                pm = fmaxf(pm, __shfl_xor(pm, 16, 64));
                pm = fmaxf(pm, __shfl_xor(pm, 32, 64));
                float mnew = fmaxf(m2, pm);
                float scl = __builtin_amdgcn_exp2f(m2 - mnew);
                m2 = mnew;
                sum_p *= scl;
                #pragma unroll
                for (int rr = 0; rr < 4; ++rr) {
                    float sb = __shfl(scl, lg * 4 + rr, 64);
                    #pragma unroll
                    for (int n = 0; n < 4; ++n) O[n][rr] *= sb;
                }
            }
            float ls = 0.f;
            #pragma unroll
            for (int mi = 0; mi < 4; ++mi)
                #pragma unroll
                for (int rr = 0; rr < 4; ++rr) {
                    s2v[mi][rr] = __builtin_amdgcn_exp2f(s2v[mi][rr] - m2);
                    ls += s2v[mi][rr];
                }
            sum_p += ls;                        // per-lane partial; no shfl

            // ---- pack P words; cross-lane shfl exchange -> A-fragments ----
            unsigned W[4][2];
            #pragma unroll
            for (int mi = 0; mi < 4; ++mi) {
                W[mi][0] = cvtpk_bf16(s2v[mi][0], s2v[mi][1]);
                W[mi][1] = cvtpk_bf16(s2v[mi][2], s2v[mi][3]);
            }
            const int lgh  = lg >> 1;
            const int bsrc = 2 * (lg & 1);
            union { unsigned u[4]; bf16x8 v; } apu0, apu1;
            #pragma unroll
            for (int jj = 0; jj < 4; ++jj) {
                int srcl = ((bsrc + (jj >> 1)) << 4) | lr;
                unsigned lo0 = __shfl(W[0][jj & 1], srcl, 64);
                unsigned hi0 = __shfl(W[1][jj & 1], srcl, 64);
                unsigned lo1 = __shfl(W[2][jj & 1], srcl, 64);
                unsigned hi1 = __shfl(W[3][jj & 1], srcl, 64);
                apu0.u[jj] = lgh ? hi0 : lo0;
                apu1.u[jj] = lgh ? hi1 : lo1;
            }

            // ---- PV: O += P @ V ----
            __builtin_amdgcn_s_setprio(1);
            #pragma unroll
            for (int n = 0; n < 4; ++n) {
                bf16x8 bv0 = *(const bf16x8*)(Vl + swz(n * 16 + lr, 0 * 64 + lg * 16));
                bf16x8 bv1 = *(const bf16x8*)(Vl + swz(n * 16 + lr, 1 * 64 + lg * 16));
                O[n] = __builtin_amdgcn_mfma_f32_16x16x32_bf16(apu0.v, bv0, O[n], 0, 0, 0);
                O[n] = __builtin_amdgcn_mfma_f32_16x16x32_bf16(apu1.v, bv1, O[n], 0, 0, 0);
            }
            __builtin_amdgcn_s_setprio(0);

            __syncthreads();                    // B: V reads done; K(si+1) drained
            if (si + 1 < s_hi) stageV(si + 1);  // V-DMA under next QK^T
        }
    }

    // ---- epilogue: write unnormalized partials ----
    float sr = sum_p;
    sr += __shfl_xor(sr, 16, 64);
    sr += __shfl_xor(sr, 32, 64);               // full row sum
    const long rbase = (long)b * TCTX + t0 + w * 16;
    #pragma unroll
    for (int rr = 0; rr < 4; ++rr) {
        int tl = lg * 4 + rr;
        long rowi = (rbase + tl) * 2 + half;
        #pragma unroll
        for (int n = 0; n < 4; ++n)
            Opart[rowi * 64 + n * 16 + lr] = O[n][rr];
    }
    if (lg == 0)
        MSum[(rbase + lr) * 2 + half] = make_float2(m2, sr);
}

// ---------------------------------------------------------------------------
// Combine: merge the two s-halves per row in log2 domain, normalize, write.
// ---------------------------------------------------------------------------
__global__ __launch_bounds__(256) void combine_kernel(
    const float* __restrict__ Opart, const float2* __restrict__ MSum,
    float* __restrict__ out)
{
    const long total = (long)NB * TCTX * KD;
    for (long idx = (long)blockIdx.x * 256 + threadIdx.x; idx < total;
         idx += (long)gridDim.x * 256) {
        long r = idx >> 6;
        int  h = (int)(idx & 63);
        float2 A = MSum[r * 2 + 0];
        float2 B = MSum[r * 2 + 1];
        float M  = fmaxf(A.x, B.x);
        float wa = __builtin_amdgcn_exp2f(A.x - M);
        float wb = __builtin_amdgcn_exp2f(B.x - M);
        float denom = A.y * wa + B.y * wb;
        float oa = Opart[(r * 2 + 0) * 64 + h];
        float ob = Opart[(r * 2 + 1) * 64 + h];
        out[idx] = (oa * wa + ob * wb) / denom;
    }
}

extern "C" void kernel_launch(void* const* d_in, const int* in_sizes, int n_in,
                              void* d_out, int out_size, void* d_ws, size_t ws_size,
                              hipStream_t stream) {
    const float* emb = (const float*)d_in[0];
    const float* kw1 = (const float*)d_in[1];
    const float* kb1 = (const float*)d_in[2];
    const float* kw2 = (const float*)d_in[3];
    const float* kb2 = (const float*)d_in[4];
    const float* qw1 = (const float*)d_in[5];
    const float* qb1 = (const float*)d_in[6];
    const float* qw2 = (const float*)d_in[7];
    const float* qb2 = (const float*)d_in[8];
    const float* vw  = (const float*)d_in[9];
    const float* vb  = (const float*)d_in[10];

    unsigned short* Qb  = (unsigned short*)d_ws;               // 4 MB
    unsigned short* Kb  = Qb + (size_t)NB * TCTX * KD;         // 4 MB
    unsigned short* Vt  = Kb + (size_t)NB * TCTX * KD;         // 4 MB, [b][h][t]
    unsigned short* W1p = Vt + (size_t)NB * TCTX * KD;         // 384 KB
    unsigned short* W2p = W1p + 196608;                        // 16 KB
    float*  Opart = (float*)(W2p + 8192);                      // 16 MB (32768 x 2 x 64)
    float2* MSum  = (float2*)(Opart + (size_t)NB * TCTX * 2 * KD);  // 512 KB

    hipLaunchKernelGGL(prep_kernel, dim3(100), dim3(256), 0, stream,
                       kw1, qw1, vw, kw2, qw2, W1p, W2p);
    hipLaunchKernelGGL(proj_kernel, dim3(512), dim3(256), 0, stream,
                       emb, W1p, W2p, kb1, kb2, qb1, qb2, vb,
                       Qb, Kb, Vt);
    hipLaunchKernelGGL(attn_kernel, dim3(2048), dim3(128), 0, stream,
                       Qb, Kb, Vt, Opart, MSum);
    hipLaunchKernelGGL(combine_kernel, dim3(2048), dim3(256), 0, stream,
                       Opart, MSum, (float*)d_out);
}

// Round 16
// 84.975 us; speedup vs baseline: 1.1149x; 1.1149x over previous
//
#include <hip/hip_runtime.h>
#include <hip/hip_bf16.h>
#include <math.h>

// Problem constants
#define NB   8
#define TCTX 4096
#define ED   1024
#define KD   64

typedef __attribute__((ext_vector_type(8))) short bf16x8;
typedef __attribute__((ext_vector_type(4))) float f32x4;

#define LOG2E  1.44269504088896340736f
#define SCALE2 (0.125f * LOG2E)          // folded into Q at projection time
#define MASK2  (-1e10f * LOG2E)          // -1e10 in log2 domain

// LGKM ops complete OUT OF ORDER: ds_read after ds_write needs lgkmcnt(0)
// (R8/R9 lesson). sched_barrier(0) stops MFMA hoisting past the asm wait.
__device__ __forceinline__ void lds_fence() {
    asm volatile("s_waitcnt lgkmcnt(0)" ::: "memory");
    __builtin_amdgcn_sched_barrier(0);
}

__device__ __forceinline__ unsigned short f2bf(float f) {
    union { float f; unsigned u; } c; c.f = f;
    return (unsigned short)((c.u + 0x7FFFu + ((c.u >> 16) & 1u)) >> 16);
}
__device__ __forceinline__ int swz(int row, int byteoff) {
    return row * 128 + (byteoff ^ ((row & 7) << 4));
}
__device__ __forceinline__ f32x4 fzero4() {
    f32x4 z; z[0] = 0.f; z[1] = 0.f; z[2] = 0.f; z[3] = 0.f; return z;
}
__device__ __forceinline__ void gl_lds16(const void* g, void* l) {
    __builtin_amdgcn_global_load_lds(
        (const __attribute__((address_space(1))) unsigned int*)g,
        (__attribute__((address_space(3))) unsigned int*)l, 16, 0, 0);
}
__device__ __forceinline__ unsigned cvtpk_bf16(float lo, float hi) {
    unsigned r;
    asm("v_cvt_pk_bf16_f32 %0, %1, %2" : "=v"(r) : "v"(lo), "v"(hi));
    return r;
}

// ---------------------------------------------------------------------------
// Prep kernel: one-time weight repack (fp32 -> bf16).  (unchanged, passing)
// ---------------------------------------------------------------------------
__global__ __launch_bounds__(256) void prep_kernel(
    const float* __restrict__ kw1, const float* __restrict__ qw1,
    const float* __restrict__ vw,  const float* __restrict__ kw2,
    const float* __restrict__ qw2,
    unsigned short* __restrict__ W1p, unsigned short* __restrict__ W2p)
{
    int idx = blockIdx.x * 256 + threadIdx.x;   // 16B-block index
    if (idx < 24576) {
        int ks = idx / 1536, rem = idx % 1536;
        int r = rem >> 3, bb = rem & 7;
        int c = bb ^ (r & 7);
        const float* src = (r < 64)  ? (kw1 + r * ED)
                         : (r < 128) ? (qw1 + (r - 64) * ED)
                                     : (vw  + (r - 128) * ED);
        src += ks * 64 + c * 8;
        unsigned short* dst = W1p + (size_t)idx * 8;
        #pragma unroll
        for (int e = 0; e < 8; ++e) dst[e] = f2bf(src[e]);
    } else if (idx < 25600) {
        int j = idx - 24576;
        int lane = j & 63, kh = (j >> 6) & 1, n = (j >> 7) & 3, kq = j >> 9;
        int row = n * 16 + (lane & 15);
        int ko  = kh * 32 + (lane >> 4) * 8;
        const float* src = (kq ? qw2 : kw2) + row * 64 + ko;
        unsigned short* dst = W2p + (size_t)j * 8;
        #pragma unroll
        for (int e = 0; e < 8; ++e) dst[e] = f2bf(src[e]);
    }
}

// ---------------------------------------------------------------------------
// Projection kernel (unchanged, passing).
// ---------------------------------------------------------------------------
__global__ __launch_bounds__(256, 2) void proj_kernel(
    const float* __restrict__ emb,
    const unsigned short* __restrict__ W1p, const unsigned short* __restrict__ W2p,
    const float* __restrict__ kb1, const float* __restrict__ kb2,
    const float* __restrict__ qb1, const float* __restrict__ qb2,
    const float* __restrict__ vb,
    unsigned short* __restrict__ Qo, unsigned short* __restrict__ Ko,
    unsigned short* __restrict__ Vt)
{
    __shared__ __align__(16) char lds[80 * 1024];

    const int tid  = threadIdx.x;
    const int lane = tid & 63;
    const int w    = tid >> 6;
    const int lr   = lane & 15;
    const int lg   = lane >> 4;
    const long r0  = (long)blockIdx.x * 64;
    const int  b   = blockIdx.x >> 6;
    const int  tb  = (blockIdx.x & 63) * 64;

    const float* embB = emb + r0 * ED;

    f32x4 acc[12];
    #pragma unroll
    for (int j = 0; j < 12; ++j) acc[j] = fzero4();

    auto stageA = [&](int buf, int ks) {
        char* Abuf = lds + buf * 16 * 1024;
        const float* eb = embB + ks * 64;
        #pragma unroll
        for (int j = 0; j < 4; ++j) {
            int chunk = j * 4 + w;
            int r = chunk * 4 + (lane >> 4);
            int c = (lane & 15) ^ (r & 7);
            gl_lds16(eb + (long)r * ED + c * 4, Abuf + chunk * 1024);
        }
    };
    auto stageB = [&](int buf, int ks) {
        char* Bbuf = lds + 32 * 1024 + buf * 24 * 1024;
        const unsigned short* wb = W1p + (size_t)ks * 12288;
        #pragma unroll
        for (int j = 0; j < 6; ++j) {
            int chunk = j * 4 + w;
            gl_lds16(wb + chunk * 512 + lane * 8, Bbuf + chunk * 1024);
        }
    };

    stageA(0, 0); stageB(0, 0);
    __syncthreads();

    int cur = 0;
    for (int ks = 0; ks < 16; ++ks) {
        if (ks < 15) { stageA(cur ^ 1, ks + 1); stageB(cur ^ 1, ks + 1); }
        char* Ac = lds + cur * 16 * 1024;
        char* Bc = lds + 32 * 1024 + cur * 24 * 1024;
        const int r = w * 16 + lr;
        #pragma unroll
        for (int kh = 0; kh < 2; ++kh) {
            int cb0 = kh * 8 + lg * 2;
            float4 fa = *(const float4*)(Ac + r * 256 + ((cb0 ^ (r & 7)) * 16));
            float4 fb = *(const float4*)(Ac + r * 256 + (((cb0 + 1) ^ (r & 7)) * 16));
            bf16x8 a;
            a[0] = (short)f2bf(fa.x); a[1] = (short)f2bf(fa.y);
            a[2] = (short)f2bf(fa.z); a[3] = (short)f2bf(fa.w);
            a[4] = (short)f2bf(fb.x); a[5] = (short)f2bf(fb.y);
            a[6] = (short)f2bf(fb.z); a[7] = (short)f2bf(fb.w);
            #pragma unroll
            for (int n = 0; n < 12; ++n) {
                bf16x8 bv = *(const bf16x8*)(Bc + swz(n * 16 + lr, kh * 64 + lg * 16));
                acc[n] = __builtin_amdgcn_mfma_f32_16x16x32_bf16(a, bv, acc[n], 0, 0, 0);
            }
        }
        __syncthreads();
        cur ^= 1;
    }

    char* H  = lds + w * 2048;
    char* VT = lds + 16 * 1024;

    #pragma unroll
    for (int kq = 0; kq < 2; ++kq) {
        const float* b1 = kq ? qb1 : kb1;
        const float* b2 = kq ? qb2 : kb2;
        unsigned short* dst = kq ? Qo : Ko;
        const float oscale = kq ? SCALE2 : 1.0f;
        #pragma unroll
        for (int n = 0; n < 4; ++n) {
            int col = n * 16 + lr;
            float bias = b1[col];
            #pragma unroll
            for (int rr = 0; rr < 4; ++rr) {
                int row = lg * 4 + rr;
                *(unsigned short*)(H + swz(row, col * 2)) =
                    f2bf(fmaxf(acc[kq * 4 + n][rr] + bias, 0.f));
            }
        }
        lds_fence();
        bf16x8 a2k0 = *(const bf16x8*)(H + swz(lr, 0 * 64 + lg * 16));
        bf16x8 a2k1 = *(const bf16x8*)(H + swz(lr, 1 * 64 + lg * 16));
        lds_fence();

        f32x4 acc2[4];
        #pragma unroll
        for (int n = 0; n < 4; ++n) acc2[n] = fzero4();
        #pragma unroll
        for (int n = 0; n < 4; ++n) {
            bf16x8 w2f0 = *(const bf16x8*)(W2p + ((kq * 4 + n) * 2 + 0) * 512 + lane * 8);
            bf16x8 w2f1 = *(const bf16x8*)(W2p + ((kq * 4 + n) * 2 + 1) * 512 + lane * 8);
            acc2[n] = __builtin_amdgcn_mfma_f32_16x16x32_bf16(a2k0, w2f0, acc2[n], 0, 0, 0);
            acc2[n] = __builtin_amdgcn_mfma_f32_16x16x32_bf16(a2k1, w2f1, acc2[n], 0, 0, 0);
        }
        #pragma unroll
        for (int n = 0; n < 4; ++n) {
            int col = n * 16 + lr;
            float bias = b2[col];
            #pragma unroll
            for (int rr = 0; rr < 4; ++rr) {
                long rg = r0 + w * 16 + lg * 4 + rr;
                dst[rg * KD + col] = f2bf(fmaxf(acc2[n][rr] + bias, 0.f) * oscale);
            }
        }
    }

    #pragma unroll
    for (int n = 0; n < 4; ++n) {
        int col = n * 16 + lr;
        float bias = vb[col];
        #pragma unroll
        for (int rr = 0; rr < 4; ++rr) {
            int tl = w * 16 + lg * 4 + rr;
            *(unsigned short*)(VT + swz(col, tl * 2)) = f2bf(acc[8 + n][rr] + bias);
        }
    }
    __syncthreads();
    #pragma unroll
    for (int it = 0; it < 2; ++it) {
        int c = it * 256 + tid;
        int h = c >> 3, c4 = c & 7;
        *(int4*)(Vt + ((long)b * KD + h) * TCTX + tb + c4 * 8) =
            *(const int4*)(VT + swz(h, c4 * 16));
    }
}

// ---------------------------------------------------------------------------
// Flash attention v10 = v6 (R12, proven best: 85.4 us total) with EXACTLY ONE
// change: XCD-pinned bid decode. b = bid&7 makes XCD i (blocks round-robin by
// bid%8) serve only batch i, whose K+Vt slices total 1MB -> resident in that
// XCD's 4MB L2. R12's decode spread 4 batches (4MB) per XCD -> L3/HBM spill
// (FETCH 10.2MB vs 6.2 ideal). All staging/schedule/P-bounce IDENTICAL to v6.
// ---------------------------------------------------------------------------
__global__ __launch_bounds__(128) void attn_kernel(
    const unsigned short* __restrict__ Qb,
    const unsigned short* __restrict__ Kb,
    const unsigned short* __restrict__ Vt,
    float* __restrict__ Opart, float2* __restrict__ MSum)
{
    __shared__ __align__(16) char lds[20 * 1024];
    // K at 0 (8KB), V at 8KB (8KB), per-wave Q/P at 16KB + w*2KB

    const int bid  = blockIdx.x;
    const int b    = bid & 7;              // XCD-pinned batch (ONLY change)
    const int half = (bid >> 3) & 1;
    const int qr   = bid >> 4;             // 0..127
    const int qi   = (qr + 127) & 127;     // heavy tiles launch first
    const int t0   = qi * 32;
    const int tid = threadIdx.x, lane = tid & 63, w = tid >> 6;
    const int lr  = lane & 15, lg = lane >> 4;
    const int tg  = t0 + w * 16 + lr;      // this lane's q-row

    char* Kl = lds;
    char* Vl = lds + 8 * 1024;
    char* QP = lds + 16 * 1024 + w * 2048;

    const unsigned short* Qg  = Qb + ((long)b * TCTX + t0 + w * 16) * KD;
    const unsigned short* Kg0 = Kb + (long)b * TCTX * KD;
    const unsigned short* Vg0 = Vt + (long)b * KD * TCTX;

    const int srow = lane >> 3;
    const int sblk = lane & 7;

    // split-s range
    const int s0q = (qi == 127) ? 0 : (qi >> 1);
    const int len = 64 - s0q;
    const int mid = s0q + ((len + 1) >> 1);
    const int s_lo = half ? mid : s0q;
    const int s_hi = half ? 64  : mid;

    auto stageK = [&](int si) {
        const unsigned short* Kg = Kg0 + si * 64 * KD;
        #pragma unroll
        for (int j = 0; j < 4; ++j) {
            int chunk = w * 4 + j;             // 2 waves split 8 chunks
            int r = chunk * 8 + srow;
            int c = sblk ^ (r & 7);
            gl_lds16(Kg + r * KD + c * 8, Kl + chunk * 1024);
        }
    };
    auto stageV = [&](int si) {
        const unsigned short* Vg = Vg0 + si * 64;
        #pragma unroll
        for (int j = 0; j < 4; ++j) {
            int chunk = w * 4 + j;
            int r = chunk * 8 + srow;
            int c = sblk ^ (r & 7);
            gl_lds16(Vg + (long)r * TCTX + c * 8, Vl + chunk * 1024);
        }
    };

    float m2 = MASK2, sum_p = 0.f;             // per-lane partial sum
    f32x4 O[4];
    #pragma unroll
    for (int n = 0; n < 4; ++n) O[n] = fzero4();

    if (s_lo < s_hi) {                          // block-uniform
        // prologue: Q + first K/V
        #pragma unroll
        for (int j = 0; j < 2; ++j) {
            int r = j * 8 + srow;
            int c = sblk ^ (r & 7);
            gl_lds16(Qg + r * KD + c * 8, QP + j * 1024);
        }
        stageK(s_lo);
        stageV(s_lo);
        __syncthreads();                        // everything resident

        bf16x8 qf[2];
        #pragma unroll
        for (int kh = 0; kh < 2; ++kh)
            qf[kh] = *(const bf16x8*)(QP + swz(lr, kh * 64 + lg * 16));

        for (int si = s_lo; si < s_hi; ++si) {
            // ---- QK^T (swapped): C[s][t], t = lr per lane ----
            f32x4 sc[4];
            #pragma unroll
            for (int mi = 0; mi < 4; ++mi) sc[mi] = fzero4();
            __builtin_amdgcn_s_setprio(1);
            #pragma unroll
            for (int kh = 0; kh < 2; ++kh) {
                #pragma unroll
                for (int mi = 0; mi < 4; ++mi) {
                    bf16x8 kf = *(const bf16x8*)(Kl + swz(mi * 16 + lr, kh * 64 + lg * 16));
                    sc[mi] = __builtin_amdgcn_mfma_f32_16x16x32_bf16(kf, qf[kh], sc[mi], 0, 0, 0);
                }
            }
            __builtin_amdgcn_s_setprio(0);

            __syncthreads();                    // A: K reads done; V(si) drained
            if (si + 1 < s_hi) stageK(si + 1);  // K-DMA under softmax+PV

            // ---- mask (scores in exp2 domain via pre-scaled Q) ----
            const int thr = tg - si * 64;       // mask if s_local <= thr
            float s2v[4][4];
            #pragma unroll
            for (int mi = 0; mi < 4; ++mi)
                #pragma unroll
                for (int rr = 0; rr < 4; ++rr) {
                    int sl = mi * 16 + lg * 4 + rr;
                    s2v[mi][rr] = (sl <= thr) ? MASK2 : sc[mi][rr];
                }

            // ---- defer-max online softmax ----
            float pml = s2v[0][0];
            #pragma unroll
            for (int mi = 0; mi < 4; ++mi)
                #pragma unroll
                for (int rr = 0; rr < 4; ++rr) pml = fmaxf(pml, s2v[mi][rr]);

            if (!__all(pml - m2 <= 8.0f)) {     // rare: full rescale
                float pm = pml;
                pm = fmaxf(pm, __shfl_xor(pm, 16, 64));
                pm = fmaxf(pm, __shfl_xor(pm, 32, 64));
                float mnew = fmaxf(m2, pm);
                float scl = __builtin_amdgcn_exp2f(m2 - mnew);
                m2 = mnew;
                sum_p *= scl;
                #pragma unroll
                for (int rr = 0; rr < 4; ++rr) {
                    float sb = __shfl(scl, lg * 4 + rr, 64);
                    #pragma unroll
                    for (int n = 0; n < 4; ++n) O[n][rr] *= sb;
                }
            }
            float ls = 0.f;
            #pragma unroll
            for (int mi = 0; mi < 4; ++mi)
                #pragma unroll
                for (int rr = 0; rr < 4; ++rr) {
                    s2v[mi][rr] = __builtin_amdgcn_exp2f(s2v[mi][rr] - m2);
                    ls += s2v[mi][rr];
                }
            sum_p += ls;

            // ---- pack P -> wave-private LDS (lgkm fence discipline) ----
            #pragma unroll
            for (int mi = 0; mi < 4; ++mi) {
                unsigned lo = cvtpk_bf16(s2v[mi][0], s2v[mi][1]);
                unsigned hi = cvtpk_bf16(s2v[mi][2], s2v[mi][3]);
                *(uint2*)(QP + swz(lr, mi * 32 + lg * 8)) = make_uint2(lo, hi);
            }
            lds_fence();                        // P writes complete
            bf16x8 ap0 = *(const bf16x8*)(QP + swz(lr, 0 * 64 + lg * 16));
            bf16x8 ap1 = *(const bf16x8*)(QP + swz(lr, 1 * 64 + lg * 16));
            lds_fence();                        // P reads returned

            // ---- PV: O += P @ V ----
            __builtin_amdgcn_s_setprio(1);
            #pragma unroll
            for (int n = 0; n < 4; ++n) {
                bf16x8 bv0 = *(const bf16x8*)(Vl + swz(n * 16 + lr, 0 * 64 + lg * 16));
                bf16x8 bv1 = *(const bf16x8*)(Vl + swz(n * 16 + lr, 1 * 64 + lg * 16));
                O[n] = __builtin_amdgcn_mfma_f32_16x16x32_bf16(ap0, bv0, O[n], 0, 0, 0);
                O[n] = __builtin_amdgcn_mfma_f32_16x16x32_bf16(ap1, bv1, O[n], 0, 0, 0);
            }
            __builtin_amdgcn_s_setprio(0);

            __syncthreads();                    // B: V reads done; K(si+1) drained
            if (si + 1 < s_hi) stageV(si + 1);  // V-DMA under next QK^T
        }
    }

    // ---- epilogue: write unnormalized partials ----
    float sr = sum_p;
    sr += __shfl_xor(sr, 16, 64);
    sr += __shfl_xor(sr, 32, 64);               // full row sum
    const long rbase = (long)b * TCTX + t0 + w * 16;
    #pragma unroll
    for (int rr = 0; rr < 4; ++rr) {
        int tl = lg * 4 + rr;
        long rowi = (rbase + tl) * 2 + half;
        #pragma unroll
        for (int n = 0; n < 4; ++n)
            Opart[rowi * 64 + n * 16 + lr] = O[n][rr];
    }
    if (lg == 0)
        MSum[(rbase + lr) * 2 + half] = make_float2(m2, sr);
}

// ---------------------------------------------------------------------------
// Combine: merge the two s-halves per row in log2 domain, normalize, write.
// ---------------------------------------------------------------------------
__global__ __launch_bounds__(256) void combine_kernel(
    const float* __restrict__ Opart, const float2* __restrict__ MSum,
    float* __restrict__ out)
{
    const long total = (long)NB * TCTX * KD;
    for (long idx = (long)blockIdx.x * 256 + threadIdx.x; idx < total;
         idx += (long)gridDim.x * 256) {
        long r = idx >> 6;
        int  h = (int)(idx & 63);
        float2 A = MSum[r * 2 + 0];
        float2 B = MSum[r * 2 + 1];
        float M  = fmaxf(A.x, B.x);
        float wa = __builtin_amdgcn_exp2f(A.x - M);
        float wb = __builtin_amdgcn_exp2f(B.x - M);
        float denom = A.y * wa + B.y * wb;
        float oa = Opart[(r * 2 + 0) * 64 + h];
        float ob = Opart[(r * 2 + 1) * 64 + h];
        out[idx] = (oa * wa + ob * wb) / denom;
    }
}

extern "C" void kernel_launch(void* const* d_in, const int* in_sizes, int n_in,
                              void* d_out, int out_size, void* d_ws, size_t ws_size,
                              hipStream_t stream) {
    const float* emb = (const float*)d_in[0];
    const float* kw1 = (const float*)d_in[1];
    const float* kb1 = (const float*)d_in[2];
    const float* kw2 = (const float*)d_in[3];
    const float* kb2 = (const float*)d_in[4];
    const float* qw1 = (const float*)d_in[5];
    const float* qb1 = (const float*)d_in[6];
    const float* qw2 = (const float*)d_in[7];
    const float* qb2 = (const float*)d_in[8];
    const float* vw  = (const float*)d_in[9];
    const float* vb  = (const float*)d_in[10];

    unsigned short* Qb  = (unsigned short*)d_ws;               // 4 MB
    unsigned short* Kb  = Qb + (size_t)NB * TCTX * KD;         // 4 MB
    unsigned short* Vt  = Kb + (size_t)NB * TCTX * KD;         // 4 MB, [b][h][t]
    unsigned short* W1p = Vt + (size_t)NB * TCTX * KD;         // 384 KB
    unsigned short* W2p = W1p + 196608;                        // 16 KB
    float*  Opart = (float*)(W2p + 8192);                      // 16 MB (32768 x 2 x 64)
    float2* MSum  = (float2*)(Opart + (size_t)NB * TCTX * 2 * KD);  // 512 KB

    hipLaunchKernelGGL(prep_kernel, dim3(100), dim3(256), 0, stream,
                       kw1, qw1, vw, kw2, qw2, W1p, W2p);
    hipLaunchKernelGGL(proj_kernel, dim3(512), dim3(256), 0, stream,
                       emb, W1p, W2p, kb1, kb2, qb1, qb2, vb,
                       Qb, Kb, Vt);
    hipLaunchKernelGGL(attn_kernel, dim3(2048), dim3(128), 0, stream,
                       Qb, Kb, Vt, Opart, MSum);
    hipLaunchKernelGGL(combine_kernel, dim3(2048), dim3(256), 0, stream,
                       Opart, MSum, (float*)d_out);
}

// Round 17
// 79.570 us; speedup vs baseline: 1.1907x; 1.0679x over previous
//
#include <hip/hip_runtime.h>
#include <hip/hip_bf16.h>
#include <math.h>

// Problem constants
#define NB   8
#define TCTX 4096
#define ED   1024
#define KD   64

typedef __attribute__((ext_vector_type(8))) short bf16x8;
typedef __attribute__((ext_vector_type(4))) float f32x4;

#define LOG2E  1.44269504088896340736f
#define SCALE2 (0.125f * LOG2E)          // folded into Q at projection time
#define MASK2  (-1e10f * LOG2E)          // -1e10 in log2 domain

// LGKM ops complete OUT OF ORDER: ds_read after ds_write needs lgkmcnt(0)
// (R8/R9 lesson). sched_barrier(0) stops MFMA hoisting past the asm wait.
__device__ __forceinline__ void lds_fence() {
    asm volatile("s_waitcnt lgkmcnt(0)" ::: "memory");
    __builtin_amdgcn_sched_barrier(0);
}

__device__ __forceinline__ unsigned short f2bf(float f) {
    union { float f; unsigned u; } c; c.f = f;
    return (unsigned short)((c.u + 0x7FFFu + ((c.u >> 16) & 1u)) >> 16);
}
__device__ __forceinline__ float bf2f(unsigned short u) {
    union { unsigned u; float f; } c; c.u = ((unsigned)u) << 16; return c.f;
}
__device__ __forceinline__ int swz(int row, int byteoff) {
    return row * 128 + (byteoff ^ ((row & 7) << 4));
}
__device__ __forceinline__ f32x4 fzero4() {
    f32x4 z; z[0] = 0.f; z[1] = 0.f; z[2] = 0.f; z[3] = 0.f; return z;
}
__device__ __forceinline__ void gl_lds16(const void* g, void* l) {
    __builtin_amdgcn_global_load_lds(
        (const __attribute__((address_space(1))) unsigned int*)g,
        (__attribute__((address_space(3))) unsigned int*)l, 16, 0, 0);
}
__device__ __forceinline__ unsigned cvtpk_bf16(float lo, float hi) {
    unsigned r;
    asm("v_cvt_pk_bf16_f32 %0, %1, %2" : "=v"(r) : "v"(lo), "v"(hi));
    return r;
}

// ---------------------------------------------------------------------------
// Prep kernel: one-time weight repack (fp32 -> bf16).  (unchanged, passing)
// ---------------------------------------------------------------------------
__global__ __launch_bounds__(256) void prep_kernel(
    const float* __restrict__ kw1, const float* __restrict__ qw1,
    const float* __restrict__ vw,  const float* __restrict__ kw2,
    const float* __restrict__ qw2,
    unsigned short* __restrict__ W1p, unsigned short* __restrict__ W2p)
{
    int idx = blockIdx.x * 256 + threadIdx.x;   // 16B-block index
    if (idx < 24576) {
        int ks = idx / 1536, rem = idx % 1536;
        int r = rem >> 3, bb = rem & 7;
        int c = bb ^ (r & 7);
        const float* src = (r < 64)  ? (kw1 + r * ED)
                         : (r < 128) ? (qw1 + (r - 64) * ED)
                                     : (vw  + (r - 128) * ED);
        src += ks * 64 + c * 8;
        unsigned short* dst = W1p + (size_t)idx * 8;
        #pragma unroll
        for (int e = 0; e < 8; ++e) dst[e] = f2bf(src[e]);
    } else if (idx < 25600) {
        int j = idx - 24576;
        int lane = j & 63, kh = (j >> 6) & 1, n = (j >> 7) & 3, kq = j >> 9;
        int row = n * 16 + (lane & 15);
        int ko  = kh * 32 + (lane >> 4) * 8;
        const float* src = (kq ? qw2 : kw2) + row * 64 + ko;
        unsigned short* dst = W2p + (size_t)j * 8;
        #pragma unroll
        for (int e = 0; e < 8; ++e) dst[e] = f2bf(src[e]);
    }
}

// ---------------------------------------------------------------------------
// Projection kernel (unchanged, passing).
// ---------------------------------------------------------------------------
__global__ __launch_bounds__(256, 2) void proj_kernel(
    const float* __restrict__ emb,
    const unsigned short* __restrict__ W1p, const unsigned short* __restrict__ W2p,
    const float* __restrict__ kb1, const float* __restrict__ kb2,
    const float* __restrict__ qb1, const float* __restrict__ qb2,
    const float* __restrict__ vb,
    unsigned short* __restrict__ Qo, unsigned short* __restrict__ Ko,
    unsigned short* __restrict__ Vt)
{
    __shared__ __align__(16) char lds[80 * 1024];

    const int tid  = threadIdx.x;
    const int lane = tid & 63;
    const int w    = tid >> 6;
    const int lr   = lane & 15;
    const int lg   = lane >> 4;
    const long r0  = (long)blockIdx.x * 64;
    const int  b   = blockIdx.x >> 6;
    const int  tb  = (blockIdx.x & 63) * 64;

    const float* embB = emb + r0 * ED;

    f32x4 acc[12];
    #pragma unroll
    for (int j = 0; j < 12; ++j) acc[j] = fzero4();

    auto stageA = [&](int buf, int ks) {
        char* Abuf = lds + buf * 16 * 1024;
        const float* eb = embB + ks * 64;
        #pragma unroll
        for (int j = 0; j < 4; ++j) {
            int chunk = j * 4 + w;
            int r = chunk * 4 + (lane >> 4);
            int c = (lane & 15) ^ (r & 7);
            gl_lds16(eb + (long)r * ED + c * 4, Abuf + chunk * 1024);
        }
    };
    auto stageB = [&](int buf, int ks) {
        char* Bbuf = lds + 32 * 1024 + buf * 24 * 1024;
        const unsigned short* wb = W1p + (size_t)ks * 12288;
        #pragma unroll
        for (int j = 0; j < 6; ++j) {
            int chunk = j * 4 + w;
            gl_lds16(wb + chunk * 512 + lane * 8, Bbuf + chunk * 1024);
        }
    };

    stageA(0, 0); stageB(0, 0);
    __syncthreads();

    int cur = 0;
    for (int ks = 0; ks < 16; ++ks) {
        if (ks < 15) { stageA(cur ^ 1, ks + 1); stageB(cur ^ 1, ks + 1); }
        char* Ac = lds + cur * 16 * 1024;
        char* Bc = lds + 32 * 1024 + cur * 24 * 1024;
        const int r = w * 16 + lr;
        #pragma unroll
        for (int kh = 0; kh < 2; ++kh) {
            int cb0 = kh * 8 + lg * 2;
            float4 fa = *(const float4*)(Ac + r * 256 + ((cb0 ^ (r & 7)) * 16));
            float4 fb = *(const float4*)(Ac + r * 256 + (((cb0 + 1) ^ (r & 7)) * 16));
            bf16x8 a;
            a[0] = (short)f2bf(fa.x); a[1] = (short)f2bf(fa.y);
            a[2] = (short)f2bf(fa.z); a[3] = (short)f2bf(fa.w);
            a[4] = (short)f2bf(fb.x); a[5] = (short)f2bf(fb.y);
            a[6] = (short)f2bf(fb.z); a[7] = (short)f2bf(fb.w);
            #pragma unroll
            for (int n = 0; n < 12; ++n) {
                bf16x8 bv = *(const bf16x8*)(Bc + swz(n * 16 + lr, kh * 64 + lg * 16));
                acc[n] = __builtin_amdgcn_mfma_f32_16x16x32_bf16(a, bv, acc[n], 0, 0, 0);
            }
        }
        __syncthreads();
        cur ^= 1;
    }

    char* H  = lds + w * 2048;
    char* VT = lds + 16 * 1024;

    #pragma unroll
    for (int kq = 0; kq < 2; ++kq) {
        const float* b1 = kq ? qb1 : kb1;
        const float* b2 = kq ? qb2 : kb2;
        unsigned short* dst = kq ? Qo : Ko;
        const float oscale = kq ? SCALE2 : 1.0f;
        #pragma unroll
        for (int n = 0; n < 4; ++n) {
            int col = n * 16 + lr;
            float bias = b1[col];
            #pragma unroll
            for (int rr = 0; rr < 4; ++rr) {
                int row = lg * 4 + rr;
                *(unsigned short*)(H + swz(row, col * 2)) =
                    f2bf(fmaxf(acc[kq * 4 + n][rr] + bias, 0.f));
            }
        }
        lds_fence();
        bf16x8 a2k0 = *(const bf16x8*)(H + swz(lr, 0 * 64 + lg * 16));
        bf16x8 a2k1 = *(const bf16x8*)(H + swz(lr, 1 * 64 + lg * 16));
        lds_fence();

        f32x4 acc2[4];
        #pragma unroll
        for (int n = 0; n < 4; ++n) acc2[n] = fzero4();
        #pragma unroll
        for (int n = 0; n < 4; ++n) {
            bf16x8 w2f0 = *(const bf16x8*)(W2p + ((kq * 4 + n) * 2 + 0) * 512 + lane * 8);
            bf16x8 w2f1 = *(const bf16x8*)(W2p + ((kq * 4 + n) * 2 + 1) * 512 + lane * 8);
            acc2[n] = __builtin_amdgcn_mfma_f32_16x16x32_bf16(a2k0, w2f0, acc2[n], 0, 0, 0);
            acc2[n] = __builtin_amdgcn_mfma_f32_16x16x32_bf16(a2k1, w2f1, acc2[n], 0, 0, 0);
        }
        #pragma unroll
        for (int n = 0; n < 4; ++n) {
            int col = n * 16 + lr;
            float bias = b2[col];
            #pragma unroll
            for (int rr = 0; rr < 4; ++rr) {
                long rg = r0 + w * 16 + lg * 4 + rr;
                dst[rg * KD + col] = f2bf(fmaxf(acc2[n][rr] + bias, 0.f) * oscale);
            }
        }
    }

    #pragma unroll
    for (int n = 0; n < 4; ++n) {
        int col = n * 16 + lr;
        float bias = vb[col];
        #pragma unroll
        for (int rr = 0; rr < 4; ++rr) {
            int tl = w * 16 + lg * 4 + rr;
            *(unsigned short*)(VT + swz(col, tl * 2)) = f2bf(acc[8 + n][rr] + bias);
        }
    }
    __syncthreads();
    #pragma unroll
    for (int it = 0; it < 2; ++it) {
        int c = it * 256 + tid;
        int h = c >> 3, c4 = c & 7;
        *(int4*)(Vt + ((long)b * KD + h) * TCTX + tb + c4 * 8) =
            *(const int4*)(VT + swz(h, c4 * 16));
    }
}

// ---------------------------------------------------------------------------
// Flash attention v11 = v6 per-wave tile code, 4-WAVE blocks (64 q-rows) +
// split-4. Each staged K/V tile now serves 4 waves (DMA bytes & issue per
// wave halve). LDS 24KB (K 8 + V 8 + 4x2 QP) -> 6 blocks/CU = 24 waves/CU.
// Grid 2048 = 8b x 64 q-tiles x 4 parts (6/CU resident). Causal (upper-tri:
// s>t valid): s-tiles [qi,64); qi==63 sweeps all (degenerate row 4095 ->
// uniform; 4-way merge preserves it). Opart stored bf16 (halves HBM).
// Schedule per tile IDENTICAL to v6 (barriers A/B, interleaved K/V staging,
// P LDS-bounce with lgkm fence discipline, setprio on MFMA).
// ---------------------------------------------------------------------------
__global__ __launch_bounds__(256) void attn_kernel(
    const unsigned short* __restrict__ Qb,
    const unsigned short* __restrict__ Kb,
    const unsigned short* __restrict__ Vt,
    unsigned short* __restrict__ Opart, float2* __restrict__ MSum)
{
    __shared__ __align__(16) char lds[24 * 1024];
    // K at 0 (8KB), V at 8KB (8KB), per-wave Q/P at 16KB + w*2KB

    const int bid  = blockIdx.x;
    const int b    = bid & 7;              // XCD-pinned batch
    const int part = (bid >> 3) & 3;
    const int qr   = bid >> 5;             // 0..63
    const int qi   = (qr + 63) & 63;       // heavy tiles launch first
    const int t0   = qi * 64;
    const int tid = threadIdx.x, lane = tid & 63, w = tid >> 6;   // w 0..3
    const int lr  = lane & 15, lg = lane >> 4;
    const int tg  = t0 + w * 16 + lr;      // this lane's q-row

    char* Kl = lds;
    char* Vl = lds + 8 * 1024;
    char* QP = lds + 16 * 1024 + w * 2048;

    const unsigned short* Qg  = Qb + ((long)b * TCTX + t0 + w * 16) * KD;
    const unsigned short* Kg0 = Kb + (long)b * TCTX * KD;
    const unsigned short* Vg0 = Vt + (long)b * KD * TCTX;

    const int srow = lane >> 3;
    const int sblk = lane & 7;

    // split-4 range of s-tiles [s0q, 64)
    const int s0q = (qi == 63) ? 0 : qi;
    const int len = 64 - s0q;
    const int s_lo = s0q + (len * part) / 4;
    const int s_hi = s0q + (len * (part + 1)) / 4;

    auto stageK = [&](int si) {
        const unsigned short* Kg = Kg0 + si * 64 * KD;
        #pragma unroll
        for (int j = 0; j < 2; ++j) {
            int chunk = w * 2 + j;             // 4 waves split 8 chunks
            int r = chunk * 8 + srow;
            int c = sblk ^ (r & 7);
            gl_lds16(Kg + r * KD + c * 8, Kl + chunk * 1024);
        }
    };
    auto stageV = [&](int si) {
        const unsigned short* Vg = Vg0 + si * 64;
        #pragma unroll
        for (int j = 0; j < 2; ++j) {
            int chunk = w * 2 + j;
            int r = chunk * 8 + srow;
            int c = sblk ^ (r & 7);
            gl_lds16(Vg + (long)r * TCTX + c * 8, Vl + chunk * 1024);
        }
    };

    float m2 = MASK2, sum_p = 0.f;             // per-lane partial sum
    f32x4 O[4];
    #pragma unroll
    for (int n = 0; n < 4; ++n) O[n] = fzero4();

    if (s_lo < s_hi) {                          // block-uniform
        // prologue: Q + first K/V
        #pragma unroll
        for (int j = 0; j < 2; ++j) {
            int r = j * 8 + srow;
            int c = sblk ^ (r & 7);
            gl_lds16(Qg + r * KD + c * 8, QP + j * 1024);
        }
        stageK(s_lo);
        stageV(s_lo);
        __syncthreads();                        // everything resident

        bf16x8 qf[2];
        #pragma unroll
        for (int kh = 0; kh < 2; ++kh)
            qf[kh] = *(const bf16x8*)(QP + swz(lr, kh * 64 + lg * 16));

        for (int si = s_lo; si < s_hi; ++si) {
            // ---- QK^T (swapped): C[s][t], t = lr per lane ----
            f32x4 sc[4];
            #pragma unroll
            for (int mi = 0; mi < 4; ++mi) sc[mi] = fzero4();
            __builtin_amdgcn_s_setprio(1);
            #pragma unroll
            for (int kh = 0; kh < 2; ++kh) {
                #pragma unroll
                for (int mi = 0; mi < 4; ++mi) {
                    bf16x8 kf = *(const bf16x8*)(Kl + swz(mi * 16 + lr, kh * 64 + lg * 16));
                    sc[mi] = __builtin_amdgcn_mfma_f32_16x16x32_bf16(kf, qf[kh], sc[mi], 0, 0, 0);
                }
            }
            __builtin_amdgcn_s_setprio(0);

            __syncthreads();                    // A: K reads done; V(si) drained
            if (si + 1 < s_hi) stageK(si + 1);  // K-DMA under softmax+PV

            // ---- mask (scores in exp2 domain via pre-scaled Q) ----
            const int thr = tg - si * 64;       // mask if s_local <= thr
            float s2v[4][4];
            #pragma unroll
            for (int mi = 0; mi < 4; ++mi)
                #pragma unroll
                for (int rr = 0; rr < 4; ++rr) {
                    int sl = mi * 16 + lg * 4 + rr;
                    s2v[mi][rr] = (sl <= thr) ? MASK2 : sc[mi][rr];
                }

            // ---- defer-max online softmax ----
            float pml = s2v[0][0];
            #pragma unroll
            for (int mi = 0; mi < 4; ++mi)
                #pragma unroll
                for (int rr = 0; rr < 4; ++rr) pml = fmaxf(pml, s2v[mi][rr]);

            if (!__all(pml - m2 <= 8.0f)) {     // rare: full rescale
                float pm = pml;
                pm = fmaxf(pm, __shfl_xor(pm, 16, 64));
                pm = fmaxf(pm, __shfl_xor(pm, 32, 64));
                float mnew = fmaxf(m2, pm);
                float scl = __builtin_amdgcn_exp2f(m2 - mnew);
                m2 = mnew;
                sum_p *= scl;
                #pragma unroll
                for (int rr = 0; rr < 4; ++rr) {
                    float sb = __shfl(scl, lg * 4 + rr, 64);
                    #pragma unroll
                    for (int n = 0; n < 4; ++n) O[n][rr] *= sb;
                }
            }
            float ls = 0.f;
            #pragma unroll
            for (int mi = 0; mi < 4; ++mi)
                #pragma unroll
                for (int rr = 0; rr < 4; ++rr) {
                    s2v[mi][rr] = __builtin_amdgcn_exp2f(s2v[mi][rr] - m2);
                    ls += s2v[mi][rr];
                }
            sum_p += ls;

            // ---- pack P -> wave-private LDS (lgkm fence discipline) ----
            #pragma unroll
            for (int mi = 0; mi < 4; ++mi) {
                unsigned lo = cvtpk_bf16(s2v[mi][0], s2v[mi][1]);
                unsigned hi = cvtpk_bf16(s2v[mi][2], s2v[mi][3]);
                *(uint2*)(QP + swz(lr, mi * 32 + lg * 8)) = make_uint2(lo, hi);
            }
            lds_fence();                        // P writes complete
            bf16x8 ap0 = *(const bf16x8*)(QP + swz(lr, 0 * 64 + lg * 16));
            bf16x8 ap1 = *(const bf16x8*)(QP + swz(lr, 1 * 64 + lg * 16));
            lds_fence();                        // P reads returned

            // ---- PV: O += P @ V ----
            __builtin_amdgcn_s_setprio(1);
            #pragma unroll
            for (int n = 0; n < 4; ++n) {
                bf16x8 bv0 = *(const bf16x8*)(Vl + swz(n * 16 + lr, 0 * 64 + lg * 16));
                bf16x8 bv1 = *(const bf16x8*)(Vl + swz(n * 16 + lr, 1 * 64 + lg * 16));
                O[n] = __builtin_amdgcn_mfma_f32_16x16x32_bf16(ap0, bv0, O[n], 0, 0, 0);
                O[n] = __builtin_amdgcn_mfma_f32_16x16x32_bf16(ap1, bv1, O[n], 0, 0, 0);
            }
            __builtin_amdgcn_s_setprio(0);

            __syncthreads();                    // B: V reads done; K(si+1) drained
            if (si + 1 < s_hi) stageV(si + 1);  // V-DMA under next QK^T
        }
    }

    // ---- epilogue: write unnormalized partials (bf16 O) ----
    float sr = sum_p;
    sr += __shfl_xor(sr, 16, 64);
    sr += __shfl_xor(sr, 32, 64);               // full row sum
    const long rbase = (long)b * TCTX + t0 + w * 16;
    #pragma unroll
    for (int rr = 0; rr < 4; ++rr) {
        int tl = lg * 4 + rr;
        long rowi = (rbase + tl) * 4 + part;
        #pragma unroll
        for (int n = 0; n < 4; ++n)
            Opart[rowi * 64 + n * 16 + lr] = f2bf(O[n][rr]);
    }
    if (lg == 0)
        MSum[(rbase + lr) * 4 + part] = make_float2(m2, sr);
}

// ---------------------------------------------------------------------------
// Combine: merge the four s-parts per row in log2 domain, normalize, write.
// ---------------------------------------------------------------------------
__global__ __launch_bounds__(256) void combine_kernel(
    const unsigned short* __restrict__ Opart, const float2* __restrict__ MSum,
    float* __restrict__ out)
{
    const long total = (long)NB * TCTX * KD;
    for (long idx = (long)blockIdx.x * 256 + threadIdx.x; idx < total;
         idx += (long)gridDim.x * 256) {
        long r = idx >> 6;
        int  h = (int)(idx & 63);
        float2 ms[4];
        #pragma unroll
        for (int p = 0; p < 4; ++p) ms[p] = MSum[r * 4 + p];
        float M = fmaxf(fmaxf(ms[0].x, ms[1].x), fmaxf(ms[2].x, ms[3].x));
        float denom = 0.f, ov = 0.f;
        #pragma unroll
        for (int p = 0; p < 4; ++p) {
            float wp = __builtin_amdgcn_exp2f(ms[p].x - M);
            denom += ms[p].y * wp;
            ov += bf2f(Opart[(r * 4 + p) * 64 + h]) * wp;
        }
        out[idx] = ov / denom;
    }
}

extern "C" void kernel_launch(void* const* d_in, const int* in_sizes, int n_in,
                              void* d_out, int out_size, void* d_ws, size_t ws_size,
                              hipStream_t stream) {
    const float* emb = (const float*)d_in[0];
    const float* kw1 = (const float*)d_in[1];
    const float* kb1 = (const float*)d_in[2];
    const float* kw2 = (const float*)d_in[3];
    const float* kb2 = (const float*)d_in[4];
    const float* qw1 = (const float*)d_in[5];
    const float* qb1 = (const float*)d_in[6];
    const float* qw2 = (const float*)d_in[7];
    const float* qb2 = (const float*)d_in[8];
    const float* vw  = (const float*)d_in[9];
    const float* vb  = (const float*)d_in[10];

    unsigned short* Qb  = (unsigned short*)d_ws;               // 4 MB
    unsigned short* Kb  = Qb + (size_t)NB * TCTX * KD;         // 4 MB
    unsigned short* Vt  = Kb + (size_t)NB * TCTX * KD;         // 4 MB, [b][h][t]
    unsigned short* W1p = Vt + (size_t)NB * TCTX * KD;         // 384 KB
    unsigned short* W2p = W1p + 196608;                        // 16 KB
    unsigned short* Opart = W2p + 8192;                        // 16 MB bf16 (32768 x 4 x 64)
    float2* MSum = (float2*)(Opart + (size_t)NB * TCTX * 4 * KD);   // 1 MB

    hipLaunchKernelGGL(prep_kernel, dim3(100), dim3(256), 0, stream,
                       kw1, qw1, vw, kw2, qw2, W1p, W2p);
    hipLaunchKernelGGL(proj_kernel, dim3(512), dim3(256), 0, stream,
                       emb, W1p, W2p, kb1, kb2, qb1, qb2, vb,
                       Qb, Kb, Vt);
    hipLaunchKernelGGL(attn_kernel, dim3(2048), dim3(256), 0, stream,
                       Qb, Kb, Vt, Opart, MSum);
    hipLaunchKernelGGL(combine_kernel, dim3(2048), dim3(256), 0, stream,
                       Opart, MSum, (float*)d_out);
}

// Round 18
// 78.710 us; speedup vs baseline: 1.2037x; 1.0109x over previous
//
#include <hip/hip_runtime.h>
#include <hip/hip_bf16.h>
#include <math.h>

// Problem constants
#define NB   8
#define TCTX 4096
#define ED   1024
#define KD   64

typedef __attribute__((ext_vector_type(8))) short bf16x8;
typedef __attribute__((ext_vector_type(4))) float f32x4;

#define LOG2E  1.44269504088896340736f
#define SCALE2 (0.125f * LOG2E)          // folded into Q at projection time
#define MASK2  (-1e10f * LOG2E)          // -1e10 in log2 domain

// LGKM ops complete OUT OF ORDER: ds_read after ds_write needs lgkmcnt(0)
// (R8/R9 lesson). sched_barrier(0) stops MFMA hoisting past the asm wait.
__device__ __forceinline__ void lds_fence() {
    asm volatile("s_waitcnt lgkmcnt(0)" ::: "memory");
    __builtin_amdgcn_sched_barrier(0);
}

__device__ __forceinline__ unsigned short f2bf(float f) {
    union { float f; unsigned u; } c; c.f = f;
    return (unsigned short)((c.u + 0x7FFFu + ((c.u >> 16) & 1u)) >> 16);
}
__device__ __forceinline__ float bf2f(unsigned short u) {
    union { unsigned u; float f; } c; c.u = ((unsigned)u) << 16; return c.f;
}
__device__ __forceinline__ int swz(int row, int byteoff) {
    return row * 128 + (byteoff ^ ((row & 7) << 4));
}
__device__ __forceinline__ f32x4 fzero4() {
    f32x4 z; z[0] = 0.f; z[1] = 0.f; z[2] = 0.f; z[3] = 0.f; return z;
}
__device__ __forceinline__ void gl_lds16(const void* g, void* l) {
    __builtin_amdgcn_global_load_lds(
        (const __attribute__((address_space(1))) unsigned int*)g,
        (__attribute__((address_space(3))) unsigned int*)l, 16, 0, 0);
}
__device__ __forceinline__ unsigned cvtpk_bf16(float lo, float hi) {
    unsigned r;
    asm("v_cvt_pk_bf16_f32 %0, %1, %2" : "=v"(r) : "v"(lo), "v"(hi));
    return r;
}

// ---------------------------------------------------------------------------
// Prep kernel: one-time weight repack (fp32 -> bf16).  (unchanged, passing)
// ---------------------------------------------------------------------------
__global__ __launch_bounds__(256) void prep_kernel(
    const float* __restrict__ kw1, const float* __restrict__ qw1,
    const float* __restrict__ vw,  const float* __restrict__ kw2,
    const float* __restrict__ qw2,
    unsigned short* __restrict__ W1p, unsigned short* __restrict__ W2p)
{
    int idx = blockIdx.x * 256 + threadIdx.x;   // 16B-block index
    if (idx < 24576) {
        int ks = idx / 1536, rem = idx % 1536;
        int r = rem >> 3, bb = rem & 7;
        int c = bb ^ (r & 7);
        const float* src = (r < 64)  ? (kw1 + r * ED)
                         : (r < 128) ? (qw1 + (r - 64) * ED)
                                     : (vw  + (r - 128) * ED);
        src += ks * 64 + c * 8;
        unsigned short* dst = W1p + (size_t)idx * 8;
        #pragma unroll
        for (int e = 0; e < 8; ++e) dst[e] = f2bf(src[e]);
    } else if (idx < 25600) {
        int j = idx - 24576;
        int lane = j & 63, kh = (j >> 6) & 1, n = (j >> 7) & 3, kq = j >> 9;
        int row = n * 16 + (lane & 15);
        int ko  = kh * 32 + (lane >> 4) * 8;
        const float* src = (kq ? qw2 : kw2) + row * 64 + ko;
        unsigned short* dst = W2p + (size_t)j * 8;
        #pragma unroll
        for (int e = 0; e < 8; ++e) dst[e] = f2bf(src[e]);
    }
}

// ---------------------------------------------------------------------------
// Projection kernel (unchanged, passing).
// ---------------------------------------------------------------------------
__global__ __launch_bounds__(256, 2) void proj_kernel(
    const float* __restrict__ emb,
    const unsigned short* __restrict__ W1p, const unsigned short* __restrict__ W2p,
    const float* __restrict__ kb1, const float* __restrict__ kb2,
    const float* __restrict__ qb1, const float* __restrict__ qb2,
    const float* __restrict__ vb,
    unsigned short* __restrict__ Qo, unsigned short* __restrict__ Ko,
    unsigned short* __restrict__ Vt)
{
    __shared__ __align__(16) char lds[80 * 1024];

    const int tid  = threadIdx.x;
    const int lane = tid & 63;
    const int w    = tid >> 6;
    const int lr   = lane & 15;
    const int lg   = lane >> 4;
    const long r0  = (long)blockIdx.x * 64;
    const int  b   = blockIdx.x >> 6;
    const int  tb  = (blockIdx.x & 63) * 64;

    const float* embB = emb + r0 * ED;

    f32x4 acc[12];
    #pragma unroll
    for (int j = 0; j < 12; ++j) acc[j] = fzero4();

    auto stageA = [&](int buf, int ks) {
        char* Abuf = lds + buf * 16 * 1024;
        const float* eb = embB + ks * 64;
        #pragma unroll
        for (int j = 0; j < 4; ++j) {
            int chunk = j * 4 + w;
            int r = chunk * 4 + (lane >> 4);
            int c = (lane & 15) ^ (r & 7);
            gl_lds16(eb + (long)r * ED + c * 4, Abuf + chunk * 1024);
        }
    };
    auto stageB = [&](int buf, int ks) {
        char* Bbuf = lds + 32 * 1024 + buf * 24 * 1024;
        const unsigned short* wb = W1p + (size_t)ks * 12288;
        #pragma unroll
        for (int j = 0; j < 6; ++j) {
            int chunk = j * 4 + w;
            gl_lds16(wb + chunk * 512 + lane * 8, Bbuf + chunk * 1024);
        }
    };

    stageA(0, 0); stageB(0, 0);
    __syncthreads();

    int cur = 0;
    for (int ks = 0; ks < 16; ++ks) {
        if (ks < 15) { stageA(cur ^ 1, ks + 1); stageB(cur ^ 1, ks + 1); }
        char* Ac = lds + cur * 16 * 1024;
        char* Bc = lds + 32 * 1024 + cur * 24 * 1024;
        const int r = w * 16 + lr;
        #pragma unroll
        for (int kh = 0; kh < 2; ++kh) {
            int cb0 = kh * 8 + lg * 2;
            float4 fa = *(const float4*)(Ac + r * 256 + ((cb0 ^ (r & 7)) * 16));
            float4 fb = *(const float4*)(Ac + r * 256 + (((cb0 + 1) ^ (r & 7)) * 16));
            bf16x8 a;
            a[0] = (short)f2bf(fa.x); a[1] = (short)f2bf(fa.y);
            a[2] = (short)f2bf(fa.z); a[3] = (short)f2bf(fa.w);
            a[4] = (short)f2bf(fb.x); a[5] = (short)f2bf(fb.y);
            a[6] = (short)f2bf(fb.z); a[7] = (short)f2bf(fb.w);
            #pragma unroll
            for (int n = 0; n < 12; ++n) {
                bf16x8 bv = *(const bf16x8*)(Bc + swz(n * 16 + lr, kh * 64 + lg * 16));
                acc[n] = __builtin_amdgcn_mfma_f32_16x16x32_bf16(a, bv, acc[n], 0, 0, 0);
            }
        }
        __syncthreads();
        cur ^= 1;
    }

    char* H  = lds + w * 2048;
    char* VT = lds + 16 * 1024;

    #pragma unroll
    for (int kq = 0; kq < 2; ++kq) {
        const float* b1 = kq ? qb1 : kb1;
        const float* b2 = kq ? qb2 : kb2;
        unsigned short* dst = kq ? Qo : Ko;
        const float oscale = kq ? SCALE2 : 1.0f;
        #pragma unroll
        for (int n = 0; n < 4; ++n) {
            int col = n * 16 + lr;
            float bias = b1[col];
            #pragma unroll
            for (int rr = 0; rr < 4; ++rr) {
                int row = lg * 4 + rr;
                *(unsigned short*)(H + swz(row, col * 2)) =
                    f2bf(fmaxf(acc[kq * 4 + n][rr] + bias, 0.f));
            }
        }
        lds_fence();
        bf16x8 a2k0 = *(const bf16x8*)(H + swz(lr, 0 * 64 + lg * 16));
        bf16x8 a2k1 = *(const bf16x8*)(H + swz(lr, 1 * 64 + lg * 16));
        lds_fence();

        f32x4 acc2[4];
        #pragma unroll
        for (int n = 0; n < 4; ++n) acc2[n] = fzero4();
        #pragma unroll
        for (int n = 0; n < 4; ++n) {
            bf16x8 w2f0 = *(const bf16x8*)(W2p + ((kq * 4 + n) * 2 + 0) * 512 + lane * 8);
            bf16x8 w2f1 = *(const bf16x8*)(W2p + ((kq * 4 + n) * 2 + 1) * 512 + lane * 8);
            acc2[n] = __builtin_amdgcn_mfma_f32_16x16x32_bf16(a2k0, w2f0, acc2[n], 0, 0, 0);
            acc2[n] = __builtin_amdgcn_mfma_f32_16x16x32_bf16(a2k1, w2f1, acc2[n], 0, 0, 0);
        }
        #pragma unroll
        for (int n = 0; n < 4; ++n) {
            int col = n * 16 + lr;
            float bias = b2[col];
            #pragma unroll
            for (int rr = 0; rr < 4; ++rr) {
                long rg = r0 + w * 16 + lg * 4 + rr;
                dst[rg * KD + col] = f2bf(fmaxf(acc2[n][rr] + bias, 0.f) * oscale);
            }
        }
    }

    #pragma unroll
    for (int n = 0; n < 4; ++n) {
        int col = n * 16 + lr;
        float bias = vb[col];
        #pragma unroll
        for (int rr = 0; rr < 4; ++rr) {
            int tl = w * 16 + lg * 4 + rr;
            *(unsigned short*)(VT + swz(col, tl * 2)) = f2bf(acc[8 + n][rr] + bias);
        }
    }
    __syncthreads();
    #pragma unroll
    for (int it = 0; it < 2; ++it) {
        int c = it * 256 + tid;
        int h = c >> 3, c4 = c & 7;
        *(int4*)(Vt + ((long)b * KD + h) * TCTX + tb + c4 * 8) =
            *(const int4*)(VT + swz(h, c4 * 16));
    }
}

// ---------------------------------------------------------------------------
// Flash attention v12 = v11 per-wave tile code, 8-WAVE blocks (128 q-rows) +
// split-4. Each staged K/V tile serves 8 waves (DMA per wave halves again).
// LDS 32KB (K 8 + V 8 + 8x2 QP); 512-thread blocks -> wave-slot-limited
// 4 blocks/CU = 32 waves/CU (hardware max, 8/SIMD). Grid 1024 = 8b x 32q x 4p.
// Causal: s0q = 2*qi (128-row q-tiles span two s-tiles); rows in the upper
// half see tile 2qi fully masked -> handled by the degenerate mechanism
// (P=1 accumulated, zeroed by scl=0 at first real tile). qi==31 sweeps all
// (row 4095 uniform). 4-way log2 merge in combine preserves everything.
// Per-tile schedule IDENTICAL to v6/v11.
// ---------------------------------------------------------------------------
__global__ __launch_bounds__(512) void attn_kernel(
    const unsigned short* __restrict__ Qb,
    const unsigned short* __restrict__ Kb,
    const unsigned short* __restrict__ Vt,
    unsigned short* __restrict__ Opart, float2* __restrict__ MSum)
{
    __shared__ __align__(16) char lds[32 * 1024];
    // K at 0 (8KB), V at 8KB (8KB), per-wave Q/P at 16KB + w*2KB

    const int bid  = blockIdx.x;
    const int b    = bid & 7;              // XCD-pinned batch
    const int part = (bid >> 3) & 3;
    const int qr   = bid >> 5;             // 0..31
    const int qi   = (qr + 31) & 31;       // heavy tiles launch first
    const int t0   = qi * 128;
    const int tid = threadIdx.x, lane = tid & 63, w = tid >> 6;   // w 0..7
    const int lr  = lane & 15, lg = lane >> 4;
    const int tg  = t0 + w * 16 + lr;      // this lane's q-row

    char* Kl = lds;
    char* Vl = lds + 8 * 1024;
    char* QP = lds + 16 * 1024 + w * 2048;

    const unsigned short* Qg  = Qb + ((long)b * TCTX + t0 + w * 16) * KD;
    const unsigned short* Kg0 = Kb + (long)b * TCTX * KD;
    const unsigned short* Vg0 = Vt + (long)b * KD * TCTX;

    const int srow = lane >> 3;
    const int sblk = lane & 7;

    // split-4 range of s-tiles [s0q, 64)
    const int s0q = (qi == 31) ? 0 : (2 * qi);
    const int len = 64 - s0q;
    const int s_lo = s0q + (len * part) / 4;
    const int s_hi = s0q + (len * (part + 1)) / 4;

    auto stageK = [&](int si) {
        const unsigned short* Kg = Kg0 + si * 64 * KD;
        int chunk = w;                         // 8 waves, 1 chunk each
        int r = chunk * 8 + srow;
        int c = sblk ^ (r & 7);
        gl_lds16(Kg + r * KD + c * 8, Kl + chunk * 1024);
    };
    auto stageV = [&](int si) {
        const unsigned short* Vg = Vg0 + si * 64;
        int chunk = w;
        int r = chunk * 8 + srow;
        int c = sblk ^ (r & 7);
        gl_lds16(Vg + (long)r * TCTX + c * 8, Vl + chunk * 1024);
    };

    float m2 = MASK2, sum_p = 0.f;             // per-lane partial sum
    f32x4 O[4];
    #pragma unroll
    for (int n = 0; n < 4; ++n) O[n] = fzero4();

    if (s_lo < s_hi) {                          // block-uniform
        // prologue: Q + first K/V
        #pragma unroll
        for (int j = 0; j < 2; ++j) {
            int r = j * 8 + srow;
            int c = sblk ^ (r & 7);
            gl_lds16(Qg + r * KD + c * 8, QP + j * 1024);
        }
        stageK(s_lo);
        stageV(s_lo);
        __syncthreads();                        // everything resident

        bf16x8 qf[2];
        #pragma unroll
        for (int kh = 0; kh < 2; ++kh)
            qf[kh] = *(const bf16x8*)(QP + swz(lr, kh * 64 + lg * 16));

        for (int si = s_lo; si < s_hi; ++si) {
            // ---- QK^T (swapped): C[s][t], t = lr per lane ----
            f32x4 sc[4];
            #pragma unroll
            for (int mi = 0; mi < 4; ++mi) sc[mi] = fzero4();
            __builtin_amdgcn_s_setprio(1);
            #pragma unroll
            for (int kh = 0; kh < 2; ++kh) {
                #pragma unroll
                for (int mi = 0; mi < 4; ++mi) {
                    bf16x8 kf = *(const bf16x8*)(Kl + swz(mi * 16 + lr, kh * 64 + lg * 16));
                    sc[mi] = __builtin_amdgcn_mfma_f32_16x16x32_bf16(kf, qf[kh], sc[mi], 0, 0, 0);
                }
            }
            __builtin_amdgcn_s_setprio(0);

            __syncthreads();                    // A: K reads done; V(si) drained
            if (si + 1 < s_hi) stageK(si + 1);  // K-DMA under softmax+PV

            // ---- mask (scores in exp2 domain via pre-scaled Q) ----
            const int thr = tg - si * 64;       // mask if s_local <= thr
            float s2v[4][4];
            #pragma unroll
            for (int mi = 0; mi < 4; ++mi)
                #pragma unroll
                for (int rr = 0; rr < 4; ++rr) {
                    int sl = mi * 16 + lg * 4 + rr;
                    s2v[mi][rr] = (sl <= thr) ? MASK2 : sc[mi][rr];
                }

            // ---- defer-max online softmax ----
            float pml = s2v[0][0];
            #pragma unroll
            for (int mi = 0; mi < 4; ++mi)
                #pragma unroll
                for (int rr = 0; rr < 4; ++rr) pml = fmaxf(pml, s2v[mi][rr]);

            if (!__all(pml - m2 <= 8.0f)) {     // rare: full rescale
                float pm = pml;
                pm = fmaxf(pm, __shfl_xor(pm, 16, 64));
                pm = fmaxf(pm, __shfl_xor(pm, 32, 64));
                float mnew = fmaxf(m2, pm);
                float scl = __builtin_amdgcn_exp2f(m2 - mnew);
                m2 = mnew;
                sum_p *= scl;
                #pragma unroll
                for (int rr = 0; rr < 4; ++rr) {
                    float sb = __shfl(scl, lg * 4 + rr, 64);
                    #pragma unroll
                    for (int n = 0; n < 4; ++n) O[n][rr] *= sb;
                }
            }
            float ls = 0.f;
            #pragma unroll
            for (int mi = 0; mi < 4; ++mi)
                #pragma unroll
                for (int rr = 0; rr < 4; ++rr) {
                    s2v[mi][rr] = __builtin_amdgcn_exp2f(s2v[mi][rr] - m2);
                    ls += s2v[mi][rr];
                }
            sum_p += ls;

            // ---- pack P -> wave-private LDS (lgkm fence discipline) ----
            #pragma unroll
            for (int mi = 0; mi < 4; ++mi) {
                unsigned lo = cvtpk_bf16(s2v[mi][0], s2v[mi][1]);
                unsigned hi = cvtpk_bf16(s2v[mi][2], s2v[mi][3]);
                *(uint2*)(QP + swz(lr, mi * 32 + lg * 8)) = make_uint2(lo, hi);
            }
            lds_fence();                        // P writes complete
            bf16x8 ap0 = *(const bf16x8*)(QP + swz(lr, 0 * 64 + lg * 16));
            bf16x8 ap1 = *(const bf16x8*)(QP + swz(lr, 1 * 64 + lg * 16));
            lds_fence();                        // P reads returned

            // ---- PV: O += P @ V ----
            __builtin_amdgcn_s_setprio(1);
            #pragma unroll
            for (int n = 0; n < 4; ++n) {
                bf16x8 bv0 = *(const bf16x8*)(Vl + swz(n * 16 + lr, 0 * 64 + lg * 16));
                bf16x8 bv1 = *(const bf16x8*)(Vl + swz(n * 16 + lr, 1 * 64 + lg * 16));
                O[n] = __builtin_amdgcn_mfma_f32_16x16x32_bf16(ap0, bv0, O[n], 0, 0, 0);
                O[n] = __builtin_amdgcn_mfma_f32_16x16x32_bf16(ap1, bv1, O[n], 0, 0, 0);
            }
            __builtin_amdgcn_s_setprio(0);

            __syncthreads();                    // B: V reads done; K(si+1) drained
            if (si + 1 < s_hi) stageV(si + 1);  // V-DMA under next QK^T
        }
    }

    // ---- epilogue: write unnormalized partials (bf16 O) ----
    float sr = sum_p;
    sr += __shfl_xor(sr, 16, 64);
    sr += __shfl_xor(sr, 32, 64);               // full row sum
    const long rbase = (long)b * TCTX + t0 + w * 16;
    #pragma unroll
    for (int rr = 0; rr < 4; ++rr) {
        int tl = lg * 4 + rr;
        long rowi = (rbase + tl) * 4 + part;
        #pragma unroll
        for (int n = 0; n < 4; ++n)
            Opart[rowi * 64 + n * 16 + lr] = f2bf(O[n][rr]);
    }
    if (lg == 0)
        MSum[(rbase + lr) * 4 + part] = make_float2(m2, sr);
}

// ---------------------------------------------------------------------------
// Combine: merge the four s-parts per row in log2 domain, normalize, write.
// ---------------------------------------------------------------------------
__global__ __launch_bounds__(256) void combine_kernel(
    const unsigned short* __restrict__ Opart, const float2* __restrict__ MSum,
    float* __restrict__ out)
{
    const long total = (long)NB * TCTX * KD;
    for (long idx = (long)blockIdx.x * 256 + threadIdx.x; idx < total;
         idx += (long)gridDim.x * 256) {
        long r = idx >> 6;
        int  h = (int)(idx & 63);
        float2 ms[4];
        #pragma unroll
        for (int p = 0; p < 4; ++p) ms[p] = MSum[r * 4 + p];
        float M = fmaxf(fmaxf(ms[0].x, ms[1].x), fmaxf(ms[2].x, ms[3].x));
        float denom = 0.f, ov = 0.f;
        #pragma unroll
        for (int p = 0; p < 4; ++p) {
            float wp = __builtin_amdgcn_exp2f(ms[p].x - M);
            denom += ms[p].y * wp;
            ov += bf2f(Opart[(r * 4 + p) * 64 + h]) * wp;
        }
        out[idx] = ov / denom;
    }
}

extern "C" void kernel_launch(void* const* d_in, const int* in_sizes, int n_in,
                              void* d_out, int out_size, void* d_ws, size_t ws_size,
                              hipStream_t stream) {
    const float* emb = (const float*)d_in[0];
    const float* kw1 = (const float*)d_in[1];
    const float* kb1 = (const float*)d_in[2];
    const float* kw2 = (const float*)d_in[3];
    const float* kb2 = (const float*)d_in[4];
    const float* qw1 = (const float*)d_in[5];
    const float* qb1 = (const float*)d_in[6];
    const float* qw2 = (const float*)d_in[7];
    const float* qb2 = (const float*)d_in[8];
    const float* vw  = (const float*)d_in[9];
    const float* vb  = (const float*)d_in[10];

    unsigned short* Qb  = (unsigned short*)d_ws;               // 4 MB
    unsigned short* Kb  = Qb + (size_t)NB * TCTX * KD;         // 4 MB
    unsigned short* Vt  = Kb + (size_t)NB * TCTX * KD;         // 4 MB, [b][h][t]
    unsigned short* W1p = Vt + (size_t)NB * TCTX * KD;         // 384 KB
    unsigned short* W2p = W1p + 196608;                        // 16 KB
    unsigned short* Opart = W2p + 8192;                        // 16 MB bf16 (32768 x 4 x 64)
    float2* MSum = (float2*)(Opart + (size_t)NB * TCTX * 4 * KD);   // 1 MB

    hipLaunchKernelGGL(prep_kernel, dim3(100), dim3(256), 0, stream,
                       kw1, qw1, vw, kw2, qw2, W1p, W2p);
    hipLaunchKernelGGL(proj_kernel, dim3(512), dim3(256), 0, stream,
                       emb, W1p, W2p, kb1, kb2, qb1, qb2, vb,
                       Qb, Kb, Vt);
    hipLaunchKernelGGL(attn_kernel, dim3(1024), dim3(512), 0, stream,
                       Qb, Kb, Vt, Opart, MSum);
    hipLaunchKernelGGL(combine_kernel, dim3(2048), dim3(256), 0, stream,
                       Opart, MSum, (float*)d_out);
}